// Round 21
// baseline (432.007 us; speedup 1.0000x reference)
//
#include <hip/hip_runtime.h>
#include <hip/hip_bf16.h>
#include <math.h>

#define EMB 1024
#define DIM_FF 4096
#define HEADS 16
#define HD 64
#define TSEQ 2048
#define BATCH 4
#define MROWS (BATCH*TSEQ)
#define LN_EPS 1e-5f
#define QSCALE 0.18033688011f  /* 0.125 * log2(e): softmax in exp2 domain */

typedef __attribute__((ext_vector_type(8))) short short8;
typedef __attribute__((ext_vector_type(4))) float f32x4;
typedef __attribute__((ext_vector_type(16))) float f32x16;

#define MFMA16(a,b,c) __builtin_amdgcn_mfma_f32_16x16x32_bf16((a),(b),(c),0,0,0)
#define MFMA32(a,b,c) __builtin_amdgcn_mfma_f32_32x32x16_bf16((a),(b),(c),0,0,0)

#define GLOBAL_AS(p) ((const __attribute__((address_space(1))) void*)(p))
#define LDS_AS(p)    ((__attribute__((address_space(3))) void*)(p))

__device__ __forceinline__ unsigned cvtpk_bf16(float lo, float hi){
    unsigned r;
    asm("v_cvt_pk_bf16_f32 %0, %1, %2" : "=v"(r) : "v"(lo), "v"(hi));
    return r;
}
// v_permlane32_swap_b32: new a = {a[0:31], b[0:31]}, new b = {a[32:63], b[32:63]}
__device__ __forceinline__ void permswap(unsigned &a, unsigned &b){
    asm("v_permlane32_swap_b32 %0, %1" : "+v"(a), "+v"(b));
}
__device__ __forceinline__ f32x4 ld4bf(const __hip_bfloat16* p){
    ushort4 u = *reinterpret_cast<const ushort4*>(p);
    union{unsigned i; float f;} c0,c1,c2,c3;
    c0.i=(unsigned)u.x<<16; c1.i=(unsigned)u.y<<16; c2.i=(unsigned)u.z<<16; c3.i=(unsigned)u.w<<16;
    f32x4 r; r[0]=c0.f; r[1]=c1.f; r[2]=c2.f; r[3]=c3.f;
    return r;
}
// XCD-partitioned block remap: XCD k owns contiguous x-range. Requires gridDim.x % 8 == 0.
__device__ __forceinline__ int2 xcd_remap(){
    int bid = blockIdx.x + blockIdx.y * gridDim.x;
    int xcd = bid & 7, i = bid >> 3;
    int xpc = gridDim.x >> 3;
    int2 r;
    r.x = xcd * xpc + (i % xpc);
    r.y = i / xpc;
    return r;
}

// ---------------- convert fp32 -> bf16 (row-major) ----------------
__global__ __launch_bounds__(256)
void cvt_bf16(const float* __restrict__ in, __hip_bfloat16* __restrict__ out, int n4){
    int i = blockIdx.x*256 + threadIdx.x;
    if (i >= n4) return;
    f32x4 v = reinterpret_cast<const f32x4*>(in)[i];
    uint2 o;
    o.x = cvtpk_bf16(v[0], v[1]);
    o.y = cvtpk_bf16(v[2], v[3]);
    *reinterpret_cast<uint2*>(reinterpret_cast<unsigned short*>(out) + (size_t)i*4) = o;
}

// ---------------- single-launch transpose+convert of ALL six weights ----------------
__global__ __launch_bounds__(256)
void prep_weights(const float* __restrict__ Wq, const float* __restrict__ Wk,
                  const float* __restrict__ Wv, const float* __restrict__ Wo,
                  const float* __restrict__ W1, const float* __restrict__ W2,
                  __hip_bfloat16* __restrict__ Wqkv_t,
                  __hip_bfloat16* __restrict__ W1_t,
                  __hip_bfloat16* __restrict__ W2_t)
{
    const int id = blockIdx.x;
    const float* in; __hip_bfloat16* dst; int R, C, bx, by;
    if (id < 4096) {
        const int m = id >> 10, t = id & 1023;
        in  = m==0 ? Wq : m==1 ? Wk : m==2 ? Wv : Wo;
        dst = Wqkv_t + (size_t)m*1024*1024;
        R = 1024; C = 1024; bx = (t & 31)*32; by = (t >> 5)*32;
    } else if (id < 8192) {
        const int t = id - 4096;
        in = W1; dst = W1_t; R = 1024; C = 4096;
        bx = (t % 128)*32; by = (t / 128)*32;
    } else {
        const int t = id - 8192;
        in = W2; dst = W2_t; R = 4096; C = 1024;
        bx = (t % 32)*32; by = (t / 32)*32;
    }
    __shared__ __hip_bfloat16 tile[32][33];
    int x = bx + threadIdx.x;
    #pragma unroll
    for (int i = threadIdx.y; i < 32; i += 8)
        tile[i][threadIdx.x] = __float2bfloat16(in[(size_t)(by+i)*C + x]);
    __syncthreads();
    int xo = by + threadIdx.x;
    #pragma unroll
    for (int i = threadIdx.y; i < 32; i += 8)
        dst[(size_t)(bx+i)*R + xo] = tile[threadIdx.x][i];
}

// ---------------- GEMM 128x128 (m97 structure + T2 swizzle + T1 remap) ----------------
// EPI: 1 = bf16 out, 3 = +bias -> bf16
template<int EPI>
__global__ __launch_bounds__(256, 4)
void gemm_bt(const __hip_bfloat16* __restrict__ A,
             const __hip_bfloat16* __restrict__ Bt,
             int M, int N, int K,
             __hip_bfloat16* __restrict__ Cb,
             const float* __restrict__ bias)
{
    __shared__ __align__(16) __hip_bfloat16 As[128*32];
    __shared__ __align__(16) __hip_bfloat16 Bs[128*32];
    const int tid = threadIdx.x;
    const int lane = tid & 63;
    const int wid = tid >> 6;
    const int wm = wid >> 1, wn = wid & 1;
    const int2 bxy = xcd_remap();
    const int row0 = bxy.x * 128;
    const int col0 = bxy.y * 128;
    const int rA = lane & 15, kg = lane >> 4;
    const int csw = (rA >> 1) & 3;

    const int lrow = lane >> 2;
    const int lcol = ((lane & 3) ^ ((lane >> 3) & 3)) << 3;

    f32x4 acc[4][4] = {};

    for (int kt = 0; kt < K; kt += 32) {
        __syncthreads();
        #pragma unroll
        for (int half = 0; half < 2; ++half) {
            const int rbase = (wid << 5) + (half << 4);
            const int r = rbase + lrow;
            __builtin_amdgcn_global_load_lds(
                GLOBAL_AS(A + (size_t)(row0 + r)*K + kt + lcol),
                LDS_AS(&As[rbase*32]), 16, 0, 0);
            __builtin_amdgcn_global_load_lds(
                GLOBAL_AS(Bt + (size_t)(col0 + r)*K + kt + lcol),
                LDS_AS(&Bs[rbase*32]), 16, 0, 0);
        }
        __syncthreads();
        short8 af[4], bfr[4];
        #pragma unroll
        for (int mi = 0; mi < 4; ++mi)
            af[mi] = *reinterpret_cast<const short8*>(&As[(wm*64 + mi*16 + rA)*32 + ((kg ^ csw)<<3)]);
        #pragma unroll
        for (int ni = 0; ni < 4; ++ni)
            bfr[ni] = *reinterpret_cast<const short8*>(&Bs[(wn*64 + ni*16 + rA)*32 + ((kg ^ csw)<<3)]);
        #pragma unroll
        for (int mi = 0; mi < 4; ++mi)
            #pragma unroll
            for (int ni = 0; ni < 4; ++ni)
                acc[mi][ni] = MFMA16(af[mi], bfr[ni], acc[mi][ni]);
    }

    #pragma unroll
    for (int mi=0; mi<4; ++mi) {
        #pragma unroll
        for (int ni=0; ni<4; ++ni) {
            #pragma unroll
            for (int j=0;j<4;++j){
                float v = acc[mi][ni][j];
                int grow = row0 + wm*64 + mi*16 + (kg<<2) + j;
                int gcol = col0 + wn*64 + ni*16 + rA;
                if constexpr (EPI==3) v += bias[gcol];
                Cb[(size_t)grow*N + gcol] = __float2bfloat16(v);
            }
        }
    }
}

// ---------------- GEMM 256x256: m97 structure, 16 waves (4x4 of 64x64), BK=32 ----------------
// Halves A/B panel traffic through L2/L3 vs 128^2 (measured wall ~10.7 TB/s).
// Per-wave code identical to gemm_bt (VGPR ~56 -> 2 blocks/CU at 1024 threads).
// EPI: 0 = QKV scatter (Q pre-scaled), 2 = +bias,relu -> bf16
template<int EPI>
__global__ __launch_bounds__(1024, 2)
void gemm256s(const __hip_bfloat16* __restrict__ A,
              const __hip_bfloat16* __restrict__ Bt,
              int M, int N, int K,
              __hip_bfloat16* __restrict__ Cb,
              const float* __restrict__ bias,
              __hip_bfloat16* __restrict__ qo,
              __hip_bfloat16* __restrict__ ko,
              __hip_bfloat16* __restrict__ vto)
{
    __shared__ __align__(16) __hip_bfloat16 As[256*32];
    __shared__ __align__(16) __hip_bfloat16 Bs[256*32];
    const int tid = threadIdx.x;
    const int lane = tid & 63;
    const int wid = tid >> 6;               // 0..15
    const int wm = wid >> 2, wn = wid & 3;  // 4x4 wave grid, 64x64 each
    const int2 bxy = xcd_remap();
    const int row0 = bxy.x * 256;
    const int col0 = bxy.y * 256;
    const int rA = lane & 15, kg = lane >> 4;
    const int csw = (rA >> 1) & 3;

    const int lrow = lane >> 2;
    const int lcol = ((lane & 3) ^ ((lane >> 3) & 3)) << 3;

    f32x4 acc[4][4] = {};

    for (int kt = 0; kt < K; kt += 32) {
        __syncthreads();
        {   // wave wid stages A rows [wid*16,+16) and B rows [wid*16,+16)
            const int rbase = wid << 4;
            const int r = rbase + lrow;
            __builtin_amdgcn_global_load_lds(
                GLOBAL_AS(A + (size_t)(row0 + r)*K + kt + lcol),
                LDS_AS(&As[rbase*32]), 16, 0, 0);
            __builtin_amdgcn_global_load_lds(
                GLOBAL_AS(Bt + (size_t)(col0 + r)*K + kt + lcol),
                LDS_AS(&Bs[rbase*32]), 16, 0, 0);
        }
        __syncthreads();
        short8 af[4], bfr[4];
        #pragma unroll
        for (int mi = 0; mi < 4; ++mi)
            af[mi] = *reinterpret_cast<const short8*>(&As[(wm*64 + mi*16 + rA)*32 + ((kg ^ csw)<<3)]);
        #pragma unroll
        for (int ni = 0; ni < 4; ++ni)
            bfr[ni] = *reinterpret_cast<const short8*>(&Bs[(wn*64 + ni*16 + rA)*32 + ((kg ^ csw)<<3)]);
        #pragma unroll
        for (int mi = 0; mi < 4; ++mi)
            #pragma unroll
            for (int ni = 0; ni < 4; ++ni)
                acc[mi][ni] = MFMA16(af[mi], bfr[ni], acc[mi][ni]);
    }

    #pragma unroll
    for (int mi=0; mi<4; ++mi) {
        #pragma unroll
        for (int ni=0; ni<4; ++ni) {
            #pragma unroll
            for (int j=0;j<4;++j){
                float v = acc[mi][ni][j];
                int grow = row0 + wm*64 + mi*16 + (kg<<2) + j;
                int gcol = col0 + wn*64 + ni*16 + rA;
                if constexpr (EPI==0) {
                    int b = grow >> 11, t = grow & 2047;
                    int which = gcol >> 10, hdx = gcol & 1023;
                    int h = hdx >> 6, d = hdx & 63;
                    int bh = b*HEADS + h;
                    if (which==0)      qo[((size_t)bh*TSEQ + t)*HD + d] = __float2bfloat16(v*QSCALE);
                    else if (which==1) ko[((size_t)bh*TSEQ + t)*HD + d] = __float2bfloat16(v);
                    else               vto[((size_t)bh*HD + d)*TSEQ + t] = __float2bfloat16(v);
                } else {
                    v += bias[gcol]; v = v > 0.0f ? v : 0.0f;
                    Cb[(size_t)grow*N + gcol] = __float2bfloat16(v);
                }
            }
        }
    }
}

// ---------------- flash attention, 32x32 MFMA, max-free exp2 softmax ----------------
__global__ __launch_bounds__(256, 4)
void attn_fwd(const __hip_bfloat16* __restrict__ q,
              const __hip_bfloat16* __restrict__ k,
              const __hip_bfloat16* __restrict__ vt,
              __hip_bfloat16* __restrict__ merged)
{
    const int wg = (blockIdx.x & 7) * 128 + (blockIdx.x >> 3);
    const int bh = wg >> 4;          // 0..63
    const int qt = wg & 15;          // 0..15
    const int wid = threadIdx.x >> 6, lane = threadIdx.x & 63;
    const int l31 = lane & 31;
    const int hi  = lane >> 5;
    const int swz = lane & 7;
    const int qrow0 = qt*128 + wid*32;
    const __hip_bfloat16* Qh = q  + (size_t)bh*TSEQ*HD;
    const __hip_bfloat16* Kh = k  + (size_t)bh*TSEQ*HD;
    const __hip_bfloat16* Vh = vt + (size_t)bh*HD*TSEQ;

    __shared__ __align__(16) __hip_bfloat16 Kl[3][64*64];
    __shared__ __align__(16) __hip_bfloat16 Vl[2][64*64];

    short8 qv[4];
    #pragma unroll
    for (int c=0;c<4;++c)
        qv[c] = *reinterpret_cast<const short8*>(Qh + (size_t)(qrow0+l31)*HD + c*16 + hi*8);

    const int lrow = lane >> 3;
    const int lslot = ((lane & 7) ^ lrow) << 3;
    const __hip_bfloat16* sK0 = Kh + (size_t)(wid*16 + lrow)*HD + lslot;
    const __hip_bfloat16* sV0 = Vh + (size_t)(wid*16 + lrow)*TSEQ + lslot;
    const int dOff = wid*16*64;

    f32x16 O0 = {}, O1 = {};
    float lpart = 0.f;
    short8 paf[4] = {};

    auto stK = [&](int t){
        const int kt = t*64;
        __hip_bfloat16* dst = &Kl[t%3][dOff];
        __builtin_amdgcn_global_load_lds(GLOBAL_AS(sK0 + (size_t)kt*HD),     LDS_AS(dst),        16, 0, 0);
        __builtin_amdgcn_global_load_lds(GLOBAL_AS(sK0 + (size_t)(kt+8)*HD), LDS_AS(dst + 8*64), 16, 0, 0);
    };
    auto stV = [&](int t){
        __hip_bfloat16* dst = &Vl[t&1][dOff];
        __builtin_amdgcn_global_load_lds(GLOBAL_AS(sV0 + t*64),          LDS_AS(dst),        16, 0, 0);
        __builtin_amdgcn_global_load_lds(GLOBAL_AS(sV0 + 8*TSEQ + t*64), LDS_AS(dst + 8*64), 16, 0, 0);
    };

    const int NT = TSEQ/64;
    stK(0); stK(1);
    asm volatile("s_waitcnt vmcnt(2)" ::: "memory");
    __builtin_amdgcn_s_barrier();

    for (int t = 0; t < NT; ++t) {
        stV(t);
        if (t+2 < NT) stK(t+2);

        const char* Kb  = (const char*)&Kl[t%3][0];
        const char* Vbp = (const char*)&Vl[(t-1)&1][0];

        f32x16 st0 = {}, st1 = {};
        #pragma unroll
        for (int c=0;c<4;++c) {
            short8 ka0 = *reinterpret_cast<const short8*>(Kb + l31*128      + (((2*c+hi)^swz)<<4));
            short8 ka1 = *reinterpret_cast<const short8*>(Kb + (32+l31)*128 + (((2*c+hi)^swz)<<4));
            st0 = MFMA32(ka0, qv[c], st0);
            st1 = MFMA32(ka1, qv[c], st1);
        }

        if (t > 0) {
            #pragma unroll
            for (int kc=0; kc<4; ++kc) {
                short8 vf0 = *reinterpret_cast<const short8*>(Vbp + l31*128      + (((2*kc+hi)^swz)<<4));
                short8 vf1 = *reinterpret_cast<const short8*>(Vbp + (32+l31)*128 + (((2*kc+hi)^swz)<<4));
                O0 = MFMA32(paf[kc], vf0, O0);
                O1 = MFMA32(paf[kc], vf1, O1);
            }
        }

        #pragma unroll
        for (int r=0;r<16;++r) {
            st0[r] = __builtin_amdgcn_exp2f(st0[r]);
            st1[r] = __builtin_amdgcn_exp2f(st1[r]);
        }
        {
            f32x16 ss = st0 + st1;
            float s8 = (((ss[0]+ss[1])+(ss[2]+ss[3]))+((ss[4]+ss[5])+(ss[6]+ss[7])))
                     + (((ss[8]+ss[9])+(ss[10]+ss[11]))+((ss[12]+ss[13])+(ss[14]+ss[15])));
            lpart += s8;
        }
        unsigned pk0[8], pk1[8];
        #pragma unroll
        for (int j=0;j<8;++j) {
            pk0[j] = cvtpk_bf16(st0[2*j], st0[2*j+1]);
            pk1[j] = cvtpk_bf16(st1[2*j], st1[2*j+1]);
        }
        #pragma unroll
        for (int kc=0; kc<4; ++kc) {
            unsigned* pkt = (kc>>1) ? pk1 : pk0;
            const int j0 = 4*(kc&1);
            unsigned a0 = pkt[j0+0], b0 = pkt[j0+2];
            unsigned a1 = pkt[j0+1], b1 = pkt[j0+3];
            permswap(a0, b0);
            permswap(a1, b1);
            union { unsigned u[4]; short8 s; } pa;
            pa.u[0] = a0; pa.u[1] = a1; pa.u[2] = b0; pa.u[3] = b1;
            paf[kc] = pa.s;
        }

        if (t+2 < NT) { asm volatile("s_waitcnt vmcnt(2)" ::: "memory"); }
        else          { asm volatile("s_waitcnt vmcnt(0)" ::: "memory"); }
        __builtin_amdgcn_s_barrier();
    }
    {
        const char* Vbp = (const char*)&Vl[(NT-1)&1][0];
        #pragma unroll
        for (int kc=0; kc<4; ++kc) {
            short8 vf0 = *reinterpret_cast<const short8*>(Vbp + l31*128      + (((2*kc+hi)^swz)<<4));
            short8 vf1 = *reinterpret_cast<const short8*>(Vbp + (32+l31)*128 + (((2*kc+hi)^swz)<<4));
            O0 = MFMA32(paf[kc], vf0, O0);
            O1 = MFMA32(paf[kc], vf1, O1);
        }
    }

    lpart += __shfl_xor(lpart, 32);
    float linv = 1.0f / lpart;
    const int b = bh >> 4, h = bh & 15;
    #pragma unroll
    for (int r=0;r<16;++r){
        int qp = (r&3) + 8*(r>>2) + 4*hi;
        float lr = __shfl(linv, qp);
        size_t base = ((size_t)(b*TSEQ + qrow0 + qp))*EMB + h*HD;
        merged[base + l31]      = __float2bfloat16(O0[r]*lr);
        merged[base + 32 + l31] = __float2bfloat16(O1[r]*lr);
    }
}

// ---------------- residual + layer norm: ONE WAVE PER ROW (no LDS, no barriers) ----------------
template<int OUTF>
__global__ __launch_bounds__(256)
void ln_res_w(const __hip_bfloat16* __restrict__ a_, const __hip_bfloat16* __restrict__ res_,
              const float* __restrict__ gain, const float* __restrict__ bias,
              float* __restrict__ outf, __hip_bfloat16* __restrict__ outb)
{
    const int wave = threadIdx.x >> 6, lane = threadIdx.x & 63;
    const int row = blockIdx.x*4 + wave;
    const size_t base = (size_t)row * EMB;
    f32x4 v[4];
    float s = 0.f;
    #pragma unroll
    for (int j=0;j<4;++j){
        const int idx = j*256 + lane*4;
        f32x4 va = ld4bf(a_ + base + idx);
        f32x4 vr = ld4bf(res_ + base + idx);
        v[j] = va + vr;
        s += (v[j][0]+v[j][1]) + (v[j][2]+v[j][3]);
    }
    #pragma unroll
    for (int off=1; off<64; off<<=1) s += __shfl_xor(s, off);
    const float mean = s * (1.0f/EMB);
    float qs = 0.f;
    #pragma unroll
    for (int j=0;j<4;++j){
        #pragma unroll
        for (int e=0;e<4;++e){ float d = v[j][e] - mean; v[j][e] = d; qs += d*d; }
    }
    #pragma unroll
    for (int off=1; off<64; off<<=1) qs += __shfl_xor(qs, off);
    const float var = qs * (1.0f/EMB);
    const float r = 1.0f/(sqrtf(var)+LN_EPS);
    #pragma unroll
    for (int j=0;j<4;++j){
        const int idx = j*256 + lane*4;
        f32x4 g  = *reinterpret_cast<const f32x4*>(gain + idx);
        f32x4 bb = *reinterpret_cast<const f32x4*>(bias + idx);
        f32x4 o;
        #pragma unroll
        for (int e=0;e<4;++e) o[e] = g[e]*(v[j][e]*r) + bb[e];
        if constexpr (OUTF) {
            *reinterpret_cast<f32x4*>(outf + base + idx) = o;
        } else {
            uint2 ob;
            ob.x = cvtpk_bf16(o[0], o[1]);
            ob.y = cvtpk_bf16(o[2], o[3]);
            *reinterpret_cast<uint2*>(reinterpret_cast<unsigned short*>(outb) + base + idx) = ob;
        }
    }
}

// ---------------- launch ----------------
extern "C" void kernel_launch(void* const* d_in, const int* in_sizes, int n_in,
                              void* d_out, int out_size, void* d_ws, size_t ws_size,
                              hipStream_t stream) {
    const float* x   = (const float*)d_in[0];
    const float* Wq  = (const float*)d_in[1];
    const float* Wk  = (const float*)d_in[2];
    const float* Wv  = (const float*)d_in[3];
    const float* Wo  = (const float*)d_in[4];
    const float* W1  = (const float*)d_in[5];
    const float* b1  = (const float*)d_in[6];
    const float* W2  = (const float*)d_in[7];
    const float* b2  = (const float*)d_in[8];
    const float* gain1 = (const float*)d_in[9];
    const float* bias1 = (const float*)d_in[10];
    const float* gain2 = (const float*)d_in[11];
    const float* bias2 = (const float*)d_in[12];

    char* ws = (char*)d_ws;
    __hip_bfloat16* Wqkv_t   = (__hip_bfloat16*)(ws + 0);          // 3072x1024 (+Wo_t right after)
    __hip_bfloat16* Wo_t     = (__hip_bfloat16*)(ws + 6291456);    // 1024x1024
    __hip_bfloat16* W1_t     = (__hip_bfloat16*)(ws + 8388608);    // 4096x1024
    __hip_bfloat16* W2_t     = (__hip_bfloat16*)(ws + 16777216);   // 1024x4096
    __hip_bfloat16* xb       = (__hip_bfloat16*)(ws + 25165824);   // 8192x1024
    __hip_bfloat16* qb       = (__hip_bfloat16*)(ws + 41943040);   // 64x2048x64
    __hip_bfloat16* kbuf     = (__hip_bfloat16*)(ws + 58720256);
    __hip_bfloat16* vtb      = (__hip_bfloat16*)(ws + 75497472);   // 64x64x2048
    __hip_bfloat16* h1       = (__hip_bfloat16*)(ws + 25165824);   // reuse xb..vtb, 8192x4096
    __hip_bfloat16* mergedb  = (__hip_bfloat16*)(ws + 92274688);   // 8192x1024
    __hip_bfloat16* ffb      = (__hip_bfloat16*)(ws + 92274688);   // reuse mergedb
    __hip_bfloat16* attendedb= (__hip_bfloat16*)(ws + 109051904);  // 8192x1024
    __hip_bfloat16* x1b      = (__hip_bfloat16*)(ws + 125829120);  // 8192x1024
    float*          outf     = (float*)d_out;

    // single-launch weight prep + x conversion
    prep_weights<<<dim3(12288), dim3(32,8), 0, stream>>>(Wq, Wk, Wv, Wo, W1, W2,
                                                         Wqkv_t, W1_t, W2_t);
    cvt_bf16<<<(MROWS*EMB/4 + 255)/256, 256, 0, stream>>>(x, xb, MROWS*EMB/4);

    // QKV projection (fused scatter, 256^2 tile halves panel traffic)
    gemm256s<0><<<dim3(MROWS/256, 3072/256), 1024, 0, stream>>>(
        xb, Wqkv_t, MROWS, 3072, EMB, nullptr, nullptr, qb, kbuf, vtb);
    // attention (32x32, 1024 blocks x 4 waves)
    attn_fwd<<<dim3(1024), 256, 0, stream>>>(qb, kbuf, vtb, mergedb);
    // output projection (128^2) -> bf16
    gemm_bt<1><<<dim3(MROWS/128, EMB/128), 256, 0, stream>>>(
        mergedb, Wo_t, MROWS, EMB, EMB, attendedb, nullptr);
    // residual + LN1 -> x1 (bf16), wave-per-row
    ln_res_w<0><<<MROWS/4, 256, 0, stream>>>(attendedb, xb, gain1, bias1, nullptr, x1b);
    // FF1: relu(x1 @ W1 + b1) -> bf16 (256^2, 512 blocks = 2/CU)
    gemm256s<2><<<dim3(MROWS/256, DIM_FF/256), 1024, 0, stream>>>(
        x1b, W1_t, MROWS, DIM_FF, EMB, h1, b1, nullptr, nullptr, nullptr);
    // FF2: h1 @ W2 + b2 -> bf16 (128^2)
    gemm_bt<3><<<dim3(MROWS/128, EMB/128), 256, 0, stream>>>(
        h1, W2_t, MROWS, EMB, DIM_FF, ffb, b2);
    // residual + LN2 -> out (f32), wave-per-row
    ln_res_w<1><<<MROWS/4, 256, 0, stream>>>(ffb, x1b, gain2, bias2, outf, nullptr);
}

// Round 22
// 391.536 us; speedup vs baseline: 1.1034x; 1.1034x over previous
//
#include <hip/hip_runtime.h>
#include <hip/hip_bf16.h>
#include <math.h>

#define EMB 1024
#define DIM_FF 4096
#define HEADS 16
#define HD 64
#define TSEQ 2048
#define BATCH 4
#define MROWS (BATCH*TSEQ)
#define LN_EPS 1e-5f
#define QSCALE 0.18033688011f  /* 0.125 * log2(e): softmax in exp2 domain */

typedef __attribute__((ext_vector_type(8))) short short8;
typedef __attribute__((ext_vector_type(4))) float f32x4;
typedef __attribute__((ext_vector_type(16))) float f32x16;

#define MFMA16(a,b,c) __builtin_amdgcn_mfma_f32_16x16x32_bf16((a),(b),(c),0,0,0)
#define MFMA32(a,b,c) __builtin_amdgcn_mfma_f32_32x32x16_bf16((a),(b),(c),0,0,0)

#define GLOBAL_AS(p) ((const __attribute__((address_space(1))) void*)(p))
#define LDS_AS(p)    ((__attribute__((address_space(3))) void*)(p))

__device__ __forceinline__ unsigned cvtpk_bf16(float lo, float hi){
    unsigned r;
    asm("v_cvt_pk_bf16_f32 %0, %1, %2" : "=v"(r) : "v"(lo), "v"(hi));
    return r;
}
// v_permlane32_swap_b32: new a = {a[0:31], b[0:31]}, new b = {a[32:63], b[32:63]}
__device__ __forceinline__ void permswap(unsigned &a, unsigned &b){
    asm("v_permlane32_swap_b32 %0, %1" : "+v"(a), "+v"(b));
}
__device__ __forceinline__ f32x4 ld4bf(const __hip_bfloat16* p){
    ushort4 u = *reinterpret_cast<const ushort4*>(p);
    union{unsigned i; float f;} c0,c1,c2,c3;
    c0.i=(unsigned)u.x<<16; c1.i=(unsigned)u.y<<16; c2.i=(unsigned)u.z<<16; c3.i=(unsigned)u.w<<16;
    f32x4 r; r[0]=c0.f; r[1]=c1.f; r[2]=c2.f; r[3]=c3.f;
    return r;
}
// XCD-partitioned block remap: XCD k owns contiguous x-range. Requires gridDim.x % 8 == 0.
__device__ __forceinline__ int2 xcd_remap(){
    int bid = blockIdx.x + blockIdx.y * gridDim.x;
    int xcd = bid & 7, i = bid >> 3;
    int xpc = gridDim.x >> 3;
    int2 r;
    r.x = xcd * xpc + (i % xpc);
    r.y = i / xpc;
    return r;
}

// ---------------- convert fp32 -> bf16 (row-major) ----------------
__global__ __launch_bounds__(256)
void cvt_bf16(const float* __restrict__ in, __hip_bfloat16* __restrict__ out, int n4){
    int i = blockIdx.x*256 + threadIdx.x;
    if (i >= n4) return;
    f32x4 v = reinterpret_cast<const f32x4*>(in)[i];
    uint2 o;
    o.x = cvtpk_bf16(v[0], v[1]);
    o.y = cvtpk_bf16(v[2], v[3]);
    *reinterpret_cast<uint2*>(reinterpret_cast<unsigned short*>(out) + (size_t)i*4) = o;
}

// ---------------- single-launch transpose+convert of ALL six weights ----------------
// flat tile ids: [0,4096) four 1024^2 (Wq,Wk,Wv,Wo); [4096,8192) W1 (1024x4096);
// [8192,12288) W2 (4096x1024). Each block does one 32x32 tile with tb(32,8).
__global__ __launch_bounds__(256)
void prep_weights(const float* __restrict__ Wq, const float* __restrict__ Wk,
                  const float* __restrict__ Wv, const float* __restrict__ Wo,
                  const float* __restrict__ W1, const float* __restrict__ W2,
                  __hip_bfloat16* __restrict__ Wqkv_t,   // 4 x 1024x1024 (Wo_t after Wv)
                  __hip_bfloat16* __restrict__ W1_t,     // 4096x1024
                  __hip_bfloat16* __restrict__ W2_t)     // 1024x4096
{
    const int id = blockIdx.x;
    const float* in; __hip_bfloat16* dst; int R, C, bx, by;
    if (id < 4096) {
        const int m = id >> 10, t = id & 1023;
        in  = m==0 ? Wq : m==1 ? Wk : m==2 ? Wv : Wo;
        dst = Wqkv_t + (size_t)m*1024*1024;
        R = 1024; C = 1024; bx = (t & 31)*32; by = (t >> 5)*32;
    } else if (id < 8192) {
        const int t = id - 4096;
        in = W1; dst = W1_t; R = 1024; C = 4096;
        bx = (t % 128)*32; by = (t / 128)*32;
    } else {
        const int t = id - 8192;
        in = W2; dst = W2_t; R = 4096; C = 1024;
        bx = (t % 32)*32; by = (t / 32)*32;
    }
    __shared__ __hip_bfloat16 tile[32][33];
    int x = bx + threadIdx.x;
    #pragma unroll
    for (int i = threadIdx.y; i < 32; i += 8)
        tile[i][threadIdx.x] = __float2bfloat16(in[(size_t)(by+i)*C + x]);
    __syncthreads();
    int xo = by + threadIdx.x;
    #pragma unroll
    for (int i = threadIdx.y; i < 32; i += 8)
        dst[(size_t)(bx+i)*R + xo] = tile[threadIdx.x][i];
}

// ---------------- GEMM 128x128 (m97 structure + T2 swizzle + T1 remap) ----------------
// EPI: 0 = QKV scatter (Q pre-scaled), 1 = bf16 out, 2 = +bias,relu -> bf16, 3 = +bias -> bf16
template<int EPI>
__global__ __launch_bounds__(256, 4)
void gemm_bt(const __hip_bfloat16* __restrict__ A,
             const __hip_bfloat16* __restrict__ Bt,
             int M, int N, int K,
             __hip_bfloat16* __restrict__ Cb,
             const float* __restrict__ bias,
             __hip_bfloat16* __restrict__ qo,
             __hip_bfloat16* __restrict__ ko,
             __hip_bfloat16* __restrict__ vto)
{
    __shared__ __align__(16) __hip_bfloat16 As[128*32];
    __shared__ __align__(16) __hip_bfloat16 Bs[128*32];
    const int tid = threadIdx.x;
    const int lane = tid & 63;
    const int wid = tid >> 6;
    const int wm = wid >> 1, wn = wid & 1;
    const int2 bxy = xcd_remap();
    const int row0 = bxy.x * 128;
    const int col0 = bxy.y * 128;
    const int rA = lane & 15, kg = lane >> 4;
    const int csw = (rA >> 1) & 3;           // read-side chunk XOR

    const int lrow = lane >> 2;
    const int lcol = ((lane & 3) ^ ((lane >> 3) & 3)) << 3;   // pre-swizzled source col

    f32x4 acc[4][4] = {};

    for (int kt = 0; kt < K; kt += 32) {
        __syncthreads();
        #pragma unroll
        for (int half = 0; half < 2; ++half) {
            const int rbase = (wid << 5) + (half << 4);
            const int r = rbase + lrow;
            __builtin_amdgcn_global_load_lds(
                GLOBAL_AS(A + (size_t)(row0 + r)*K + kt + lcol),
                LDS_AS(&As[rbase*32]), 16, 0, 0);
            __builtin_amdgcn_global_load_lds(
                GLOBAL_AS(Bt + (size_t)(col0 + r)*K + kt + lcol),
                LDS_AS(&Bs[rbase*32]), 16, 0, 0);
        }
        __syncthreads();
        short8 af[4], bfr[4];
        #pragma unroll
        for (int mi = 0; mi < 4; ++mi)
            af[mi] = *reinterpret_cast<const short8*>(&As[(wm*64 + mi*16 + rA)*32 + ((kg ^ csw)<<3)]);
        #pragma unroll
        for (int ni = 0; ni < 4; ++ni)
            bfr[ni] = *reinterpret_cast<const short8*>(&Bs[(wn*64 + ni*16 + rA)*32 + ((kg ^ csw)<<3)]);
        #pragma unroll
        for (int mi = 0; mi < 4; ++mi)
            #pragma unroll
            for (int ni = 0; ni < 4; ++ni)
                acc[mi][ni] = MFMA16(af[mi], bfr[ni], acc[mi][ni]);
    }

    #pragma unroll
    for (int mi=0; mi<4; ++mi) {
        #pragma unroll
        for (int ni=0; ni<4; ++ni) {
            #pragma unroll
            for (int j=0;j<4;++j){
                float v = acc[mi][ni][j];
                int grow = row0 + wm*64 + mi*16 + (kg<<2) + j;
                int gcol = col0 + wn*64 + ni*16 + rA;
                if constexpr (EPI==0) {
                    int b = grow >> 11, t = grow & 2047;
                    int which = gcol >> 10, hdx = gcol & 1023;
                    int h = hdx >> 6, d = hdx & 63;
                    int bh = b*HEADS + h;
                    if (which==0)      qo[((size_t)bh*TSEQ + t)*HD + d] = __float2bfloat16(v*QSCALE);
                    else if (which==1) ko[((size_t)bh*TSEQ + t)*HD + d] = __float2bfloat16(v);
                    else               vto[((size_t)bh*HD + d)*TSEQ + t] = __float2bfloat16(v);
                } else if constexpr (EPI==2) {
                    v += bias[gcol]; v = v > 0.0f ? v : 0.0f;
                    Cb[(size_t)grow*N + gcol] = __float2bfloat16(v);
                } else {
                    if constexpr (EPI==3) v += bias[gcol];
                    Cb[(size_t)grow*N + gcol] = __float2bfloat16(v);
                }
            }
        }
    }
}

// ---------------- flash attention, 32x32 MFMA, max-free exp2 softmax ----------------
// PV(t-1) interleaves with QK(t). T4: K staged 2 tiles ahead (triple buffer),
// counted vmcnt(2) BEFORE the raw s_barrier; P redistribution via permlane32_swap.
__global__ __launch_bounds__(256, 4)
void attn_fwd(const __hip_bfloat16* __restrict__ q,
              const __hip_bfloat16* __restrict__ k,
              const __hip_bfloat16* __restrict__ vt,
              __hip_bfloat16* __restrict__ merged)
{
    const int wg = (blockIdx.x & 7) * 128 + (blockIdx.x >> 3);
    const int bh = wg >> 4;          // 0..63
    const int qt = wg & 15;          // 0..15
    const int wid = threadIdx.x >> 6, lane = threadIdx.x & 63;
    const int l31 = lane & 31;
    const int hi  = lane >> 5;
    const int swz = lane & 7;
    const int qrow0 = qt*128 + wid*32;
    const __hip_bfloat16* Qh = q  + (size_t)bh*TSEQ*HD;
    const __hip_bfloat16* Kh = k  + (size_t)bh*TSEQ*HD;
    const __hip_bfloat16* Vh = vt + (size_t)bh*HD*TSEQ;

    __shared__ __align__(16) __hip_bfloat16 Kl[3][64*64];   // 24 KB (triple)
    __shared__ __align__(16) __hip_bfloat16 Vl[2][64*64];   // 16 KB

    short8 qv[4];
    #pragma unroll
    for (int c=0;c<4;++c)
        qv[c] = *reinterpret_cast<const short8*>(Qh + (size_t)(qrow0+l31)*HD + c*16 + hi*8);

    const int lrow = lane >> 3;
    const int lslot = ((lane & 7) ^ lrow) << 3;
    const __hip_bfloat16* sK0 = Kh + (size_t)(wid*16 + lrow)*HD + lslot;
    const __hip_bfloat16* sV0 = Vh + (size_t)(wid*16 + lrow)*TSEQ + lslot;
    const int dOff = wid*16*64;

    f32x16 O0 = {}, O1 = {};
    float lpart = 0.f;
    short8 paf[4] = {};

    auto stK = [&](int t){
        const int kt = t*64;
        __hip_bfloat16* dst = &Kl[t%3][dOff];
        __builtin_amdgcn_global_load_lds(GLOBAL_AS(sK0 + (size_t)kt*HD),     LDS_AS(dst),        16, 0, 0);
        __builtin_amdgcn_global_load_lds(GLOBAL_AS(sK0 + (size_t)(kt+8)*HD), LDS_AS(dst + 8*64), 16, 0, 0);
    };
    auto stV = [&](int t){
        __hip_bfloat16* dst = &Vl[t&1][dOff];
        __builtin_amdgcn_global_load_lds(GLOBAL_AS(sV0 + t*64),          LDS_AS(dst),        16, 0, 0);
        __builtin_amdgcn_global_load_lds(GLOBAL_AS(sV0 + 8*TSEQ + t*64), LDS_AS(dst + 8*64), 16, 0, 0);
    };

    const int NT = TSEQ/64;
    stK(0); stK(1);
    asm volatile("s_waitcnt vmcnt(2)" ::: "memory");
    __builtin_amdgcn_s_barrier();

    for (int t = 0; t < NT; ++t) {
        stV(t);
        if (t+2 < NT) stK(t+2);

        const char* Kb  = (const char*)&Kl[t%3][0];
        const char* Vbp = (const char*)&Vl[(t-1)&1][0];

        f32x16 st0 = {}, st1 = {};
        #pragma unroll
        for (int c=0;c<4;++c) {
            short8 ka0 = *reinterpret_cast<const short8*>(Kb + l31*128      + (((2*c+hi)^swz)<<4));
            short8 ka1 = *reinterpret_cast<const short8*>(Kb + (32+l31)*128 + (((2*c+hi)^swz)<<4));
            st0 = MFMA32(ka0, qv[c], st0);
            st1 = MFMA32(ka1, qv[c], st1);
        }

        if (t > 0) {
            #pragma unroll
            for (int kc=0; kc<4; ++kc) {
                short8 vf0 = *reinterpret_cast<const short8*>(Vbp + l31*128      + (((2*kc+hi)^swz)<<4));
                short8 vf1 = *reinterpret_cast<const short8*>(Vbp + (32+l31)*128 + (((2*kc+hi)^swz)<<4));
                O0 = MFMA32(paf[kc], vf0, O0);
                O1 = MFMA32(paf[kc], vf1, O1);
            }
        }

        #pragma unroll
        for (int r=0;r<16;++r) {
            st0[r] = __builtin_amdgcn_exp2f(st0[r]);
            st1[r] = __builtin_amdgcn_exp2f(st1[r]);
        }
        {
            f32x16 ss = st0 + st1;
            float s8 = (((ss[0]+ss[1])+(ss[2]+ss[3]))+((ss[4]+ss[5])+(ss[6]+ss[7])))
                     + (((ss[8]+ss[9])+(ss[10]+ss[11]))+((ss[12]+ss[13])+(ss[14]+ss[15])));
            lpart += s8;
        }
        unsigned pk0[8], pk1[8];
        #pragma unroll
        for (int j=0;j<8;++j) {
            pk0[j] = cvtpk_bf16(st0[2*j], st0[2*j+1]);
            pk1[j] = cvtpk_bf16(st1[2*j], st1[2*j+1]);
        }
        #pragma unroll
        for (int kc=0; kc<4; ++kc) {
            unsigned* pkt = (kc>>1) ? pk1 : pk0;
            const int j0 = 4*(kc&1);
            unsigned a0 = pkt[j0+0], b0 = pkt[j0+2];
            unsigned a1 = pkt[j0+1], b1 = pkt[j0+3];
            permswap(a0, b0);
            permswap(a1, b1);
            union { unsigned u[4]; short8 s; } pa;
            pa.u[0] = a0; pa.u[1] = a1; pa.u[2] = b0; pa.u[3] = b1;
            paf[kc] = pa.s;
        }

        if (t+2 < NT) { asm volatile("s_waitcnt vmcnt(2)" ::: "memory"); }
        else          { asm volatile("s_waitcnt vmcnt(0)" ::: "memory"); }
        __builtin_amdgcn_s_barrier();
    }
    {
        const char* Vbp = (const char*)&Vl[(NT-1)&1][0];
        #pragma unroll
        for (int kc=0; kc<4; ++kc) {
            short8 vf0 = *reinterpret_cast<const short8*>(Vbp + l31*128      + (((2*kc+hi)^swz)<<4));
            short8 vf1 = *reinterpret_cast<const short8*>(Vbp + (32+l31)*128 + (((2*kc+hi)^swz)<<4));
            O0 = MFMA32(paf[kc], vf0, O0);
            O1 = MFMA32(paf[kc], vf1, O1);
        }
    }

    lpart += __shfl_xor(lpart, 32);
    float linv = 1.0f / lpart;
    const int b = bh >> 4, h = bh & 15;
    #pragma unroll
    for (int r=0;r<16;++r){
        int qp = (r&3) + 8*(r>>2) + 4*hi;
        float lr = __shfl(linv, qp);
        size_t base = ((size_t)(b*TSEQ + qrow0 + qp))*EMB + h*HD;
        merged[base + l31]      = __float2bfloat16(O0[r]*lr);
        merged[base + 32 + l31] = __float2bfloat16(O1[r]*lr);
    }
}

// ---------------- residual + layer norm: ONE WAVE PER ROW (no LDS, no barriers) ----------------
// a, res are bf16; OUTF: write f32 to outf, else bf16 to outb.
template<int OUTF>
__global__ __launch_bounds__(256)
void ln_res_w(const __hip_bfloat16* __restrict__ a_, const __hip_bfloat16* __restrict__ res_,
              const float* __restrict__ gain, const float* __restrict__ bias,
              float* __restrict__ outf, __hip_bfloat16* __restrict__ outb)
{
    const int wave = threadIdx.x >> 6, lane = threadIdx.x & 63;
    const int row = blockIdx.x*4 + wave;
    const size_t base = (size_t)row * EMB;
    f32x4 v[4];
    float s = 0.f;
    #pragma unroll
    for (int j=0;j<4;++j){
        const int idx = j*256 + lane*4;
        f32x4 va = ld4bf(a_ + base + idx);
        f32x4 vr = ld4bf(res_ + base + idx);
        v[j] = va + vr;
        s += (v[j][0]+v[j][1]) + (v[j][2]+v[j][3]);
    }
    #pragma unroll
    for (int off=1; off<64; off<<=1) s += __shfl_xor(s, off);
    const float mean = s * (1.0f/EMB);
    float qs = 0.f;
    #pragma unroll
    for (int j=0;j<4;++j){
        #pragma unroll
        for (int e=0;e<4;++e){ float d = v[j][e] - mean; v[j][e] = d; qs += d*d; }
    }
    #pragma unroll
    for (int off=1; off<64; off<<=1) qs += __shfl_xor(qs, off);
    const float var = qs * (1.0f/EMB);
    const float r = 1.0f/(sqrtf(var)+LN_EPS);
    #pragma unroll
    for (int j=0;j<4;++j){
        const int idx = j*256 + lane*4;
        f32x4 g  = *reinterpret_cast<const f32x4*>(gain + idx);
        f32x4 bb = *reinterpret_cast<const f32x4*>(bias + idx);
        f32x4 o;
        #pragma unroll
        for (int e=0;e<4;++e) o[e] = g[e]*(v[j][e]*r) + bb[e];
        if constexpr (OUTF) {
            *reinterpret_cast<f32x4*>(outf + base + idx) = o;
        } else {
            uint2 ob;
            ob.x = cvtpk_bf16(o[0], o[1]);
            ob.y = cvtpk_bf16(o[2], o[3]);
            *reinterpret_cast<uint2*>(reinterpret_cast<unsigned short*>(outb) + base + idx) = ob;
        }
    }
}

// ---------------- launch ----------------
extern "C" void kernel_launch(void* const* d_in, const int* in_sizes, int n_in,
                              void* d_out, int out_size, void* d_ws, size_t ws_size,
                              hipStream_t stream) {
    const float* x   = (const float*)d_in[0];
    const float* Wq  = (const float*)d_in[1];
    const float* Wk  = (const float*)d_in[2];
    const float* Wv  = (const float*)d_in[3];
    const float* Wo  = (const float*)d_in[4];
    const float* W1  = (const float*)d_in[5];
    const float* b1  = (const float*)d_in[6];
    const float* W2  = (const float*)d_in[7];
    const float* b2  = (const float*)d_in[8];
    const float* gain1 = (const float*)d_in[9];
    const float* bias1 = (const float*)d_in[10];
    const float* gain2 = (const float*)d_in[11];
    const float* bias2 = (const float*)d_in[12];

    char* ws = (char*)d_ws;
    __hip_bfloat16* Wqkv_t   = (__hip_bfloat16*)(ws + 0);          // 3072x1024 (+Wo_t right after)
    __hip_bfloat16* Wo_t     = (__hip_bfloat16*)(ws + 6291456);    // 1024x1024
    __hip_bfloat16* W1_t     = (__hip_bfloat16*)(ws + 8388608);    // 4096x1024
    __hip_bfloat16* W2_t     = (__hip_bfloat16*)(ws + 16777216);   // 1024x4096
    __hip_bfloat16* xb       = (__hip_bfloat16*)(ws + 25165824);   // 8192x1024
    __hip_bfloat16* qb       = (__hip_bfloat16*)(ws + 41943040);   // 64x2048x64
    __hip_bfloat16* kbuf     = (__hip_bfloat16*)(ws + 58720256);
    __hip_bfloat16* vtb      = (__hip_bfloat16*)(ws + 75497472);   // 64x64x2048
    __hip_bfloat16* h1       = (__hip_bfloat16*)(ws + 25165824);   // reuse xb..vtb, 8192x4096
    __hip_bfloat16* mergedb  = (__hip_bfloat16*)(ws + 92274688);   // 8192x1024
    __hip_bfloat16* ffb      = (__hip_bfloat16*)(ws + 92274688);   // reuse mergedb
    __hip_bfloat16* attendedb= (__hip_bfloat16*)(ws + 109051904);  // 8192x1024
    __hip_bfloat16* x1b      = (__hip_bfloat16*)(ws + 125829120);  // 8192x1024
    float*          outf     = (float*)d_out;

    // single-launch weight prep + x conversion
    prep_weights<<<dim3(12288), dim3(32,8), 0, stream>>>(Wq, Wk, Wv, Wo, W1, W2,
                                                         Wqkv_t, W1_t, W2_t);
    cvt_bf16<<<(MROWS*EMB/4 + 255)/256, 256, 0, stream>>>(x, xb, MROWS*EMB/4);

    // QKV projection (fused scatter, 128^2, 1536 blocks)
    gemm_bt<0><<<dim3(MROWS/128, 3072/128), 256, 0, stream>>>(
        xb, Wqkv_t, MROWS, 3072, EMB, nullptr, nullptr, qb, kbuf, vtb);
    // attention (32x32, 1024 blocks x 4 waves)
    attn_fwd<<<dim3(1024), 256, 0, stream>>>(qb, kbuf, vtb, mergedb);
    // output projection (128^2) -> bf16
    gemm_bt<1><<<dim3(MROWS/128, EMB/128), 256, 0, stream>>>(
        mergedb, Wo_t, MROWS, EMB, EMB, attendedb, nullptr, nullptr, nullptr, nullptr);
    // residual + LN1 -> x1 (bf16), wave-per-row
    ln_res_w<0><<<MROWS/4, 256, 0, stream>>>(attendedb, xb, gain1, bias1, nullptr, x1b);
    // FF1: relu(x1 @ W1 + b1) -> bf16 (128^2, 2048 blocks)
    gemm_bt<2><<<dim3(MROWS/128, DIM_FF/128), 256, 0, stream>>>(
        x1b, W1_t, MROWS, DIM_FF, EMB, h1, b1, nullptr, nullptr, nullptr);
    // FF2: h1 @ W2 + b2 -> bf16 (128^2)
    gemm_bt<3><<<dim3(MROWS/128, EMB/128), 256, 0, stream>>>(
        h1, W2_t, MROWS, EMB, DIM_FF, ffb, b2, nullptr, nullptr, nullptr);
    // residual + LN2 -> out (f32), wave-per-row
    ln_res_w<1><<<MROWS/4, 256, 0, stream>>>(ffb, x1b, gain2, bias2, outf, nullptr);
}